// Round 7
// baseline (63.229 us; speedup 1.0000x reference)
//
#include <hip/hip_runtime.h>
#include <cstddef>

// YOLO decode: out[b, ((h*W+w)*3+a), attr] = f(x[b, a*85+attr, h, w])
//   attr 0: (sigmoid(v) + w) * stride
//   attr 1: (sigmoid(v) + h) * stride
//   attr 2: exp(v) * anchor_w_px
//   attr 3: exp(v) * anchor_h_px
//   attr 4: sigmoid(v)
//   attr>=5: sigmoid(idf[attr-5] * v)
//
// Block = 512 threads, TWO 32-pixel tiles per block, software-pipelined
// through ONE LDS buffer with raw s_barrier + lgkmcnt(0)-only waits (never
// vmcnt(0) at a barrier): tile1's global loads are issued between B1 and B2
// and stay in flight across the barrier while tile0's stores drain.
// Staging: 8 consecutive lanes own one channel (128B contiguous / channel).
// LDS [p][c] stride 255 (conflict-free both sides); image pre-shifted so
// copy-out is aligned ds_read_b128 + aligned dwordx4 stores.

#define NATTR 85
#define NCH 255
#define TILE 32
#define QPT 8
#define NSTG (NCH * QPT)  // 2040 staging quads per full tile
#define NTHR 512

static constexpr int TOTROWS = (76 * 76 + 38 * 38 + 19 * 19) * 3;  // 22743

static __device__ __forceinline__ float sigmoidf_(float x) {
  return 1.0f / (1.0f + __expf(-x));
}

// lgkmcnt-only barrier: LDS ordered, global loads stay in flight.
static __device__ __forceinline__ void bar_lgkm() {
  asm volatile("s_waitcnt lgkmcnt(0)" ::: "memory");
  __builtin_amdgcn_s_barrier();
  asm volatile("" ::: "memory");
}

template <int SCALE>
struct Cfg {
  static constexpr int W = (SCALE == 0) ? 76 : (SCALE == 1) ? 38 : 19;
  static constexpr int HW = W * W;
  static constexpr int TILES = (HW + TILE - 1) / TILE;  // 181 / 46 / 12
  static constexpr float STRIDE = 608.0f / (float)W;
  static constexpr int ROWBASE =
      (SCALE == 0) ? 0 : (SCALE == 1) ? 76 * 76 * 3 : (76 * 76 * 3 + 38 * 38 * 3);
  static constexpr float AW0 = (SCALE == 0) ? 10.f : (SCALE == 1) ? 30.f : 116.f;
  static constexpr float AW1 = (SCALE == 0) ? 16.f : (SCALE == 1) ? 62.f : 156.f;
  static constexpr float AW2 = (SCALE == 0) ? 33.f : (SCALE == 1) ? 59.f : 373.f;
  static constexpr float AH0 = (SCALE == 0) ? 13.f : (SCALE == 1) ? 61.f : 90.f;
  static constexpr float AH1 = (SCALE == 0) ? 30.f : (SCALE == 1) ? 45.f : 198.f;
  static constexpr float AH2 = (SCALE == 0) ? 23.f : (SCALE == 1) ? 119.f : 326.f;
};

template <int SCALE>
static __device__ __forceinline__ float xf(int a, int attr, int p, float v,
                                           const float* __restrict__ sidf) {
  using C = Cfg<SCALE>;
  if (attr >= 5) return sigmoidf_(sidf[attr - 5] * v);  // 80/85 channels
  if (attr == 4) return sigmoidf_(v);
  if (attr == 2) {
    const float aw = (a == 0) ? C::AW0 : (a == 1) ? C::AW1 : C::AW2;
    return __expf(v) * aw;
  }
  if (attr == 3) {
    const float ah = (a == 0) ? C::AH0 : (a == 1) ? C::AH1 : C::AH2;
    return __expf(v) * ah;
  }
  const int h = p / C::W;  // constexpr W -> magic mul
  const int w = p - h * C::W;
  return (sigmoidf_(v) + (float)((attr == 0) ? w : h)) * C::STRIDE;
}

struct TState {
  const float* src;
  size_t off;
  int p0, np, head, s;
};

template <int SCALE>
static __device__ __forceinline__ void tile_init(int idx, const float* __restrict__ x,
                                                 TState& st) {
  using C = Cfg<SCALE>;
  const int b = idx / C::TILES;
  const int t = idx - b * C::TILES;
  st.p0 = t * TILE;
  const int rem = C::HW - st.p0;
  st.np = rem < TILE ? rem : TILE;
  st.off = ((size_t)b * TOTROWS + C::ROWBASE + (size_t)st.p0 * 3) * NATTR;
  st.head = (int)((4 - (st.off & 3)) & 3);
  st.s = (4 - st.head) & 3;
  st.src = x + (size_t)b * ((size_t)C::HW * NCH) + st.p0;
}

template <int SCALE>
static __device__ __forceinline__ void tile_load(const TState& st, float4 (&r)[4]) {
  using C = Cfg<SCALE>;
  if ((C::HW % 4 == 0) && st.np == TILE) {
#pragma unroll
    for (int k = 0; k < 4; ++k) {
      int i = (int)threadIdx.x + NTHR * k;
      i = i < NSTG ? i : NSTG - 1;  // clamp: branch-free in-bounds load
      const int c = i >> 3, v = i & 7;
      r[k] = *reinterpret_cast<const float4*>(st.src + (size_t)c * C::HW + 4 * v);
    }
  } else {
    float* rf = reinterpret_cast<float*>(r);
#pragma unroll
    for (int k = 0; k < 16; ++k) {
      const int i = (int)threadIdx.x + NTHR * k;
      const int c = i >> 5, p = i & 31;
      if (c < NCH && p < st.np) rf[k] = st.src[(size_t)c * C::HW + p];
    }
  }
}

template <int SCALE>
static __device__ __forceinline__ void tile_xform(const TState& st, float4 (&r)[4],
                                                  const float* __restrict__ sidf,
                                                  float* __restrict__ lds) {
  using C = Cfg<SCALE>;
  if ((C::HW % 4 == 0) && st.np == TILE) {
#pragma unroll
    for (int k = 0; k < 4; ++k) {
      const int i = (int)threadIdx.x + NTHR * k;
      if (i < NSTG) {
        const int c = i >> 3, v = i & 7;
        const int a = c / NATTR;
        const int attr = c - a * NATTR;
        const int pb = st.p0 + 4 * v;
        float* dl = lds + st.s + (4 * v) * NCH + c;  // [p][c], stride 255
        dl[0]       = xf<SCALE>(a, attr, pb + 0, r[k].x, sidf);
        dl[NCH]     = xf<SCALE>(a, attr, pb + 1, r[k].y, sidf);
        dl[2 * NCH] = xf<SCALE>(a, attr, pb + 2, r[k].z, sidf);
        dl[3 * NCH] = xf<SCALE>(a, attr, pb + 3, r[k].w, sidf);
      }
    }
  } else {
    const float* rf = reinterpret_cast<const float*>(r);
#pragma unroll
    for (int k = 0; k < 16; ++k) {
      const int i = (int)threadIdx.x + NTHR * k;
      const int c = i >> 5, p = i & 31;
      if (c < NCH && p < st.np) {
        const int a = c / NATTR;
        const int attr = c - a * NATTR;
        lds[st.s + p * NCH + c] = xf<SCALE>(a, attr, st.p0 + p, rf[k], sidf);
      }
    }
  }
}

static __device__ __forceinline__ void tile_read(const TState& st,
                                                 const float* __restrict__ lds,
                                                 float4 (&tt)[4], float& hv, float& tv) {
  const int total = st.np * NCH;
  if ((st.np & 3) == 0) {
    const int nvec = (total - st.head) >> 2;
    const float4* lv = reinterpret_cast<const float4*>(lds + st.s + st.head);  // aligned
    if ((int)threadIdx.x < st.head) hv = lds[st.s + threadIdx.x];
#pragma unroll
    for (int k = 0; k < 4; ++k) {
      int v = (int)threadIdx.x + NTHR * k;
      v = v < nvec ? v : nvec - 1;
      tt[k] = lv[v];
    }
    const int done = st.head + 4 * nvec;
    if ((int)threadIdx.x < total - done) tv = lds[st.s + done + threadIdx.x];
  } else {
    float* tf = reinterpret_cast<float*>(tt);
#pragma unroll
    for (int m = 0; m < 5; ++m) {
      const int j = (int)threadIdx.x + NTHR * m;
      if (j < total) tf[m] = lds[st.s + j];
    }
  }
}

static __device__ __forceinline__ void tile_store(const TState& st, float4 (&tt)[4],
                                                  float hv, float tv,
                                                  float* __restrict__ out) {
  const int total = st.np * NCH;
  float* dst = out + st.off;
  if ((st.np & 3) == 0) {
    const int nvec = (total - st.head) >> 2;
    if ((int)threadIdx.x < st.head) dst[threadIdx.x] = hv;
#pragma unroll
    for (int k = 0; k < 4; ++k) {
      const int v = (int)threadIdx.x + NTHR * k;
      if (v < nvec) *reinterpret_cast<float4*>(dst + st.head + 4 * v) = tt[k];
    }
    const int done = st.head + 4 * nvec;
    if ((int)threadIdx.x < total - done) dst[done + threadIdx.x] = tv;
  } else {
    const float* tf = reinterpret_cast<const float*>(tt);
#pragma unroll
    for (int m = 0; m < 5; ++m) {
      const int j = (int)threadIdx.x + NTHR * m;
      if (j < total) dst[j] = tf[m];
    }
  }
}

template <int SCALE>
static __device__ __forceinline__ void pipeline2(int i0, const float* __restrict__ x,
                                                 const float* __restrict__ sidf,
                                                 float* __restrict__ out,
                                                 float* __restrict__ lds) {
  TState s0, s1;
  tile_init<SCALE>(i0, x, s0);
  tile_init<SCALE>(i0 + 1, x, s1);
  float4 r[4], tt[4];
  float hv = 0.f, tv = 0.f;

  tile_load<SCALE>(s0, r);
  tile_xform<SCALE>(s0, r, sidf, lds);
  bar_lgkm();                    // B1: t0 LDS image visible
  tile_read(s0, lds, tt, hv, tv);
  tile_load<SCALE>(s1, r);       // prefetch: stays in flight across B2
  bar_lgkm();                    // B2: all t0 LDS reads done -> buffer free
  tile_store(s0, tt, hv, tv, out);
  tile_xform<SCALE>(s1, r, sidf, lds);  // vmcnt wait on r inserted here
  bar_lgkm();                    // B1': t1 LDS image visible
  tile_read(s1, lds, tt, hv, tv);
  tile_store(s1, tt, hv, tv, out);
}

__global__ __launch_bounds__(512, 8) void yolo_all(
    const float* __restrict__ x0, const float* __restrict__ x1,
    const float* __restrict__ x2, const float* __restrict__ idf,
    float* __restrict__ out, int bs) {
  __shared__ __align__(16) float lds[TILE * NCH + 4];
  __shared__ float sidf[80];
  if (threadIdx.x < 80) sidf[threadIdx.x] = idf[threadIdx.x];
  __syncthreads();

  // Tile pair (2*blk, 2*blk+1); per-scale tile counts (181/46/12 x bs) are all
  // even, and region starts (0, 2896, 3632 for bs=16) are even -> pairs never
  // straddle scales, so the SCALE branch is block-uniform (barriers safe).
  const int nb0 = Cfg<0>::TILES * bs;
  const int nb1 = Cfg<1>::TILES * bs;
  const int g0 = blockIdx.x * 2;
  if (g0 < nb0) {
    pipeline2<0>(g0, x0, sidf, out, lds);
  } else if (g0 < nb0 + nb1) {
    pipeline2<1>(g0 - nb0, x1, sidf, out, lds);
  } else {
    pipeline2<2>(g0 - nb0 - nb1, x2, sidf, out, lds);
  }
}

extern "C" void kernel_launch(void* const* d_in, const int* in_sizes, int n_in,
                              void* d_out, int out_size, void* d_ws, size_t ws_size,
                              hipStream_t stream) {
  const float* x0 = (const float*)d_in[0];
  const float* x1 = (const float*)d_in[1];
  const float* x2 = (const float*)d_in[2];
  const float* idf = (const float*)d_in[3];
  float* out = (float*)d_out;

  const int bs = in_sizes[0] / (NCH * 76 * 76);  // 16
  const int ntiles = (Cfg<0>::TILES + Cfg<1>::TILES + Cfg<2>::TILES) * bs;  // 3824
  const int nb = ntiles / 2;  // 1912 blocks, 2 tiles each

  yolo_all<<<dim3(nb), dim3(512), 0, stream>>>(x0, x1, x2, idf, out, bs);
}